// Round 4
// baseline (10010.611 us; speedup 1.0000x reference)
//
#include <hip/hip_runtime.h>

// LSTM: S=4096, I=64, H=1024, O=1, fp32.
// Persistent cooperative kernel, 128 blocks x 512 threads (r6 skeleton).
// Round-9: weights in REGISTERS (LDS-sourced reads are not remat-able).
// Round-10 (inbox fan-out) REGRESSED; round-11 (wave dataflow) REGRESSED 2x;
// round-12 (depth-2 rotated poll) REGRESSED 13%. Lesson: any extra poll
// traffic queues at the MALL and delays store visibility. r0 poll restored.
// Round-13 change (this round): FINE-GRAINED CHUNK FLAGS, NO IN-LOOP BARRIER.
//   Wave w's own poll slots are exactly h-chunks w and w+8, so each wave
//   detects two full chunks itself (parallel, direct from global, no relay).
//   After detect: write values to hs, release-fence, set 2 tagged LDS flags.
//   Consume chunks 0..15 in order, spinning on the per-chunk flag
//   (workgroup-scope same-address ds_read broadcast, ~10cy when set): FMAs
//   on early chunks overlap/hide late line arrivals (MALL jitter max-of-128
//   coupling was previously paid at the barrier by every wave).
//   Overwrite safety without barrier (r2 induction, HW-validated): global
//   tag s on any chunk => owner consumed all s-1 => every block published
//   s-1 => every wave consumed s-2 => parity buffer s-2 is dead.
//   Publish path byte-identical to r0: tagged 8B atoms, wave-0 LDS gather,
//   ONE coalesced 64B line store per block (WRITE_SIZE must stay 32768 KB).

#define SEQ_LEN 4096
#define HID 1024
#define NBLK 128
#define TPB 512
#define HPB 8      // h-indices per block (one per wave)

#define ALD(p)    __hip_atomic_load((p), __ATOMIC_RELAXED, __HIP_MEMORY_SCOPE_AGENT)
#define AST(p,v)  __hip_atomic_store((p), (v), __ATOMIC_RELAXED, __HIP_MEMORY_SCOPE_AGENT)
#define LLDU(p)   __hip_atomic_load((p), __ATOMIC_RELAXED, __HIP_MEMORY_SCOPE_WORKGROUP)
#define LSTU(p,v) __hip_atomic_store((p), (v), __ATOMIC_RELAXED, __HIP_MEMORY_SCOPE_WORKGROUP)

__device__ __forceinline__ float fast_sigmoid(float x) {
    return __builtin_amdgcn_rcpf(1.0f + __builtin_amdgcn_exp2f(-1.4426950408889634f * x));
}
__device__ __forceinline__ float fast_tanh(float x) {
    return fmaf(-2.0f, __builtin_amdgcn_rcpf(1.0f + __builtin_amdgcn_exp2f(2.8853900817779268f * x)), 1.0f);
}

// ws: unsigned long long slots[2][1024]. {tag:32 | fp32 bits}. Zero-init:
// buffer0 tag0/val0 == h_0 = 0 (correct); buffer1 receives odd tags.
__global__ void lstm_init_kernel(unsigned long long* ws) {
    int t = threadIdx.x;
    #pragma unroll
    for (int k = 0; k < 8; ++k) ws[t + 256 * k] = 0ull;
}

__global__ __launch_bounds__(TPB, 1) void lstm_persistent_kernel(
    const float* __restrict__ input,   // [4096][64]
    const float* __restrict__ W_ih,    // [4096][64]
    const float* __restrict__ W_hh,    // [4096][1024]
    const float* __restrict__ b_ih,    // [4096]
    const float* __restrict__ b_hh,    // [4096]
    const float* __restrict__ W_lin,   // [1][1024]
    const float* __restrict__ b_lin,   // [1]
    float* __restrict__ out,           // [1]
    unsigned long long* __restrict__ ws)
{
    const int t   = threadIdx.x;
    const int b   = blockIdx.x;
    const int w   = t >> 6;      // wave in block (0..7)
    const int l   = t & 63;      // lane
    const int grp = l >> 4;      // gate q (i,f,g,o)
    const int sl  = l & 15;      // sub-lane within gate group
    const int j   = HPB * b + w; // owned h index
    const int row = grp * HID + j;

    unsigned long long* slot0 = ws;          // even tags
    unsigned long long* slot1 = ws + HID;    // odd tags

    __shared__ float4 wlds4[17 * TPB];       // 136 KB weight staging
    __shared__ float  hs[2][HID];            // double-buffered h (8 KB)
    __shared__ unsigned fl[2][16];           // tagged per-chunk ready flags
    __shared__ unsigned long long pub[HPB];  // tagged intra-block handoff
    __shared__ float  red[HPB];

    // ---- stage this block's 32 gate-rows into LDS ----
    {
        const float4* Whh4 = (const float4*)(W_hh + (size_t)row * HID);
        #pragma unroll
        for (int c = 0; c < 16; ++c)
            wlds4[c * TPB + t] = Whh4[sl + 16 * c];     // W_hh[row][64c+4sl..+3]
        wlds4[16 * TPB + t] = ((const float4*)(W_ih + (size_t)row * 64))[sl];
    }
    float bias[4];
    #pragma unroll
    for (int q = 0; q < 4; ++q) bias[q] = b_ih[q * HID + j] + b_hh[q * HID + j];
    if (t < HPB) pub[t] = 0ull;
    if (t < 32) ((unsigned*)fl)[t] = 0xFFFFFFFFu;   // never a valid tag
    __syncthreads();   // one-time: weights staged, pub+flags initialized

    // ---- LDS -> named registers (NOT remat-able: RA must keep in VGPRs) ----
    const float4 W0  = wlds4[ 0 * TPB + t];
    const float4 W1  = wlds4[ 1 * TPB + t];
    const float4 W2  = wlds4[ 2 * TPB + t];
    const float4 W3  = wlds4[ 3 * TPB + t];
    const float4 W4  = wlds4[ 4 * TPB + t];
    const float4 W5  = wlds4[ 5 * TPB + t];
    const float4 W6  = wlds4[ 6 * TPB + t];
    const float4 W7  = wlds4[ 7 * TPB + t];
    const float4 W8  = wlds4[ 8 * TPB + t];
    const float4 W9  = wlds4[ 9 * TPB + t];
    const float4 W10 = wlds4[10 * TPB + t];
    const float4 W11 = wlds4[11 * TPB + t];
    const float4 W12 = wlds4[12 * TPB + t];
    const float4 W13 = wlds4[13 * TPB + t];
    const float4 W14 = wlds4[14 * TPB + t];
    const float4 W15 = wlds4[15 * TPB + t];
    const float4 W16 = wlds4[16 * TPB + t];   // W_ih fragment

    const float4* xin4 = (const float4*)input;
    float c_state = 0.0f;

    for (int s = 0; s < SEQ_LEN; ++s) {
        const int par = s & 1;
        float4 x4 = xin4[s * 16 + sl];   // issue before poll (cacheable)

        // ---- poll own 2 tagged slots == h-chunks w and w+8 (r0 poll) ----
        unsigned long long* rs = par ? slot1 : slot0;
        const unsigned tag = (unsigned)s;
        unsigned long long v0, v1;
        bool q0 = false, q1 = false;
        do {
            if (!q0) { v0 = ALD(&rs[t      ]); q0 = ((unsigned)(v0 >> 32) == tag); }
            if (!q1) { v1 = ALD(&rs[t + 512]); q1 = ((unsigned)(v1 >> 32) == tag); }
        } while (!(q0 && q1));
        // loop exit is wave-wide (SIMT): both chunks fully arrived

        float* hsb = hs[par];
        hsb[t      ] = __uint_as_float((unsigned)(v0 & 0xffffffffull));
        hsb[t + 512] = __uint_as_float((unsigned)(v1 & 0xffffffffull));
        __atomic_signal_fence(__ATOMIC_RELEASE);   // keep value stores above flags
        if (l == 0) {                               // same-wave LDS ops retire in order
            LSTU(&fl[par][w],     tag);
            LSTU(&fl[par][w + 8], tag);
        }

        // ---- consume: x-term first, then chunks 0..15 gated by flags ----
        const float4* hs4 = (const float4*)hsb;
        volatile unsigned* flp = &fl[par][0];
        float a0 = W16.x * x4.x, a1 = W16.y * x4.y,
              a2 = W16.z * x4.z, a3 = W16.w * x4.w;
        #define FMA_CHUNK(Wc, c, acc) {                                        \
            while (LLDU((unsigned*)&flp[(c)]) != tag) { }                      \
            __atomic_signal_fence(__ATOMIC_ACQUIRE);                           \
            float4 h4_ = hs4[16 * (c) + sl];                                   \
            acc = fmaf((Wc).x, h4_.x, acc); acc = fmaf((Wc).y, h4_.y, acc);    \
            acc = fmaf((Wc).z, h4_.z, acc); acc = fmaf((Wc).w, h4_.w, acc); }
        FMA_CHUNK(W0,  0, a0) FMA_CHUNK(W1,  1, a1)
        FMA_CHUNK(W2,  2, a2) FMA_CHUNK(W3,  3, a3)
        FMA_CHUNK(W4,  4, a0) FMA_CHUNK(W5,  5, a1)
        FMA_CHUNK(W6,  6, a2) FMA_CHUNK(W7,  7, a3)
        FMA_CHUNK(W8,  8, a0) FMA_CHUNK(W9,  9, a1)
        FMA_CHUNK(W10, 10, a2) FMA_CHUNK(W11, 11, a3)
        FMA_CHUNK(W12, 12, a0) FMA_CHUNK(W13, 13, a1)
        FMA_CHUNK(W14, 14, a2) FMA_CHUNK(W15, 15, a3)
        #undef FMA_CHUNK
        float acc = (a0 + a1) + (a2 + a3);

        // reduce across 16 lanes of the gate group
        acc += __shfl_xor(acc, 1);
        acc += __shfl_xor(acc, 2);
        acc += __shfl_xor(acc, 4);
        acc += __shfl_xor(acc, 8);

        float gi = __shfl(acc, 0)  + bias[0];
        float gf = __shfl(acc, 16) + bias[1];
        float gg = __shfl(acc, 32) + bias[2];
        float go = __shfl(acc, 48) + bias[3];

        float ig = fast_sigmoid(gi);
        float fg = fast_sigmoid(gf);
        float cg = fast_tanh(gg);
        float og = fast_sigmoid(go);
        c_state  = fmaf(fg, c_state, ig * cg);
        float hn = og * fast_tanh(c_state);

        // ---- intra-block handoff: wave w lane 0 posts tagged hn to LDS ----
        const unsigned ntag = (unsigned)(s + 1);
        if (l == 0) {
            unsigned long long pv = ((unsigned long long)ntag << 32) |
                                    (unsigned long long)__float_as_uint(hn);
            __hip_atomic_store(&pub[w], pv, __ATOMIC_RELAXED, __HIP_MEMORY_SCOPE_WORKGROUP);
        }
        // ---- wave 0 lanes 0..7 gather the 8 words, publish one 64B line ----
        if (w == 0 && l < HPB) {
            unsigned long long pv;
            do {
                pv = __hip_atomic_load(&pub[l], __ATOMIC_RELAXED, __HIP_MEMORY_SCOPE_WORKGROUP);
            } while ((unsigned)(pv >> 32) != ntag);
            unsigned long long* wsl = par ? slot0 : slot1;   // buffer (s+1)&1
            AST(&wsl[HPB * b + l], pv);
        }
        // no trailing barrier: parity buffers + tag induction bound skew
    }

    // ---- final projection: h_4096 (tag 4096, even -> slot0) . W_lin + b_lin ----
    if (b == 0) {
        const unsigned tag = (unsigned)SEQ_LEN;
        unsigned long long v0, v1;
        bool q0 = false, q1 = false;
        do {
            if (!q0) { v0 = ALD(&slot0[t      ]); q0 = ((unsigned)(v0 >> 32) == tag); }
            if (!q1) { v1 = ALD(&slot0[t + 512]); q1 = ((unsigned)(v1 >> 32) == tag); }
        } while (!(q0 && q1));
        float p = __uint_as_float((unsigned)(v0 & 0xffffffffull)) * W_lin[t] +
                  __uint_as_float((unsigned)(v1 & 0xffffffffull)) * W_lin[t + 512];
        #pragma unroll
        for (int m = 32; m >= 1; m >>= 1) p += __shfl_xor(p, m);
        if (l == 0) red[w] = p;
        __syncthreads();
        if (t == 0) {
            float r = 0.f;
            #pragma unroll
            for (int k = 0; k < HPB; ++k) r += red[k];
            out[0] = r + b_lin[0];
        }
    }
}

extern "C" void kernel_launch(void* const* d_in, const int* in_sizes, int n_in,
                              void* d_out, int out_size, void* d_ws, size_t ws_size,
                              hipStream_t stream) {
    const float* input = (const float*)d_in[0];
    const float* W_ih  = (const float*)d_in[1];
    const float* W_hh  = (const float*)d_in[2];
    const float* b_ih  = (const float*)d_in[3];
    const float* b_hh  = (const float*)d_in[4];
    const float* W_lin = (const float*)d_in[5];
    const float* b_lin = (const float*)d_in[6];
    float* out = (float*)d_out;
    unsigned long long* ws = (unsigned long long*)d_ws;

    hipLaunchKernelGGL(lstm_init_kernel, dim3(1), dim3(256), 0, stream, ws);

    void* args[] = { (void*)&input, (void*)&W_ih, (void*)&W_hh, (void*)&b_ih,
                     (void*)&b_hh, (void*)&W_lin, (void*)&b_lin, (void*)&out, (void*)&ws };
    (void)hipLaunchCooperativeKernel((void*)lstm_persistent_kernel, dim3(NBLK), dim3(TPB),
                                     args, 0, stream);
}